// Round 4
// baseline (73.742 us; speedup 1.0000x reference)
//
#include <hip/hip_runtime.h>
#include <hip/hip_cooperative_groups.h>

namespace cg = cooperative_groups;

#define NREL1 12   // NREL + 1 relation matrices
#define NN    128  // neighbours
#define EE    128  // in-features
#define FF    128  // out-features
#define BV    192  // B * V
#define RK    (NREL1 * EE)   // 1536

// ws layout (floats): [0,1536) Wa1 rows, [1536,3072) Wa2 rows, [4096, 4096+BV*RK) S
#define WS_WA 0
#define WS_S  4096

// Cooperative kernel, 192 blocks x 1024 threads (1 block/CU, all co-resident).
// Stage W : wa[row] = W_row . a1/a2 distributed over the grid (W read ONCE),
//           zero out[].                                          -> grid.sync
// Stage A : per-edge logits (float4, 2 edges per wave per iter)
// Stage B : softmax + indicator mask
// Stage C : relation-bucketed scatter (8 LDS copies) -> S[bv] to ws -> grid.sync
// Stage D : tiled GEMM out[192x128] += S[192x1536] @ W[1536x128]
//           grid remapped to 12 bv-tiles x 4 f-tiles x 4 K-splits, atomicAdd.
__global__ __launch_bounds__(1024) void gat_coop(const float* __restrict__ fe,
                                                 const float* __restrict__ ne,
                                                 const int* __restrict__ widx,
                                                 const float* __restrict__ ind,
                                                 const float* __restrict__ W,
                                                 const float* __restrict__ a,
                                                 float* __restrict__ out,
                                                 float* __restrict__ ws) {
    cg::grid_group grid = cg::this_grid();

    __shared__ float wa1[RK];           // 6 KB
    __shared__ float wa2[RK];           // 6 KB
    __shared__ float e_lds[NN];
    __shared__ float attn[NN];
    __shared__ int   idx[NN];
    __shared__ float s8[8][RK];         // 48 KB
    __shared__ float s_tile[16][384];   // 24 KB
    __shared__ float w_tile[384][32];   // 48 KB

    const int blk  = blockIdx.x;
    const int tid  = threadIdx.x;
    const int wave = tid >> 6;
    const int lane = tid & 63;

    // ---- Stage W: grid-distributed wa precompute + zero out ----
    if (wave < 8) {
        const int row = blk * 8 + wave;            // 192*8 = 1536 rows
        const float2 wv = *(const float2*)(W + (size_t)row * FF + lane * 2);
        const float2 a1 = *(const float2*)(a + lane * 2);
        const float2 a2 = *(const float2*)(a + FF + lane * 2);
        float d1 = wv.x * a1.x + wv.y * a1.y;
        float d2 = wv.x * a2.x + wv.y * a2.y;
#pragma unroll
        for (int off = 32; off; off >>= 1) {
            d1 += __shfl_xor(d1, off);
            d2 += __shfl_xor(d2, off);
        }
        if (lane == 0) {
            ws[WS_WA + row]      = d1;
            ws[WS_WA + RK + row] = d2;
        }
    } else if (wave == 8) {
        *(float2*)(out + blk * FF + lane * 2) = make_float2(0.f, 0.f);
    }
    grid.sync();

    // ---- stage wa -> LDS, idx -> LDS, zero scatter accumulators ----
    for (int i = tid; i < RK; i += 1024) {
        wa1[i] = ws[WS_WA + i];
        wa2[i] = ws[WS_WA + RK + i];
    }
    if (tid < NN) idx[tid] = widx[blk * NN + tid];
    for (int i = tid; i < 8 * RK; i += 1024) (&s8[0][0])[i] = 0.f;
    __syncthreads();

    const float* ne_bv = ne + (size_t)blk * NN * EE;
    const float* fe_bv = fe + (size_t)blk * NN * EE;

    // ---- Stage A: logits, 2 edges per wave-iteration via float4 ----
    {
        const int sub = lane >> 5;   // 0/1 -> which row of the pair
        const int l32 = lane & 31;
#pragma unroll
        for (int p = 0; p < 4; ++p) {
            const int n  = wave * 8 + p * 2;
            const int nе = n + sub;
            const int r  = idx[nе];
            const float4 nv = *(const float4*)(ne_bv + n * EE + lane * 4);
            const float4 fv = *(const float4*)(fe_bv + n * EE + lane * 4);
            const float4 w1 = *(const float4*)(wa1 + r * EE + l32 * 4);
            const float4 w2 = *(const float4*)(wa2 + r * EE + l32 * 4);
            float d = nv.x * w1.x + nv.y * w1.y + nv.z * w1.z + nv.w * w1.w
                    + fv.x * w2.x + fv.y * w2.y + fv.z * w2.z + fv.w * w2.w;
#pragma unroll
            for (int off = 16; off; off >>= 1) d += __shfl_xor(d, off);
            if (l32 == 0) e_lds[nе] = d > 0.f ? d : 0.2f * d;
        }
    }
    __syncthreads();

    // ---- Stage B: softmax over neighbours + indicator mask (wave 0) ----
    if (tid < 64) {
        float v0 = e_lds[tid], v1 = e_lds[tid + 64];
        float m = fmaxf(v0, v1);
#pragma unroll
        for (int off = 32; off; off >>= 1) m = fmaxf(m, __shfl_xor(m, off));
        float ex0 = expf(v0 - m), ex1 = expf(v1 - m);
        float ssum = ex0 + ex1;
#pragma unroll
        for (int off = 32; off; off >>= 1) ssum += __shfl_xor(ssum, off);
        float inv = 1.f / ssum;
        attn[tid]      = ex0 * inv * ind[blk * NN + tid];
        attn[tid + 64] = ex1 * inv * ind[blk * NN + tid + 64];
    }
    __syncthreads();

    // ---- Stage C: s[r][e] += attn[n]*ne[n][e], 8 independent copies ----
    {
        const int c = tid >> 7;
        const int e = tid & 127;
        float* sc = s8[c];
        for (int n = c; n < NN; n += 8)
            sc[idx[n] * EE + e] += attn[n] * ne_bv[n * EE + e];
    }
    __syncthreads();

    // reduce 8 copies, S[bv] -> ws
    for (int k = tid; k < RK; k += 1024) {
        float v = s8[0][k] + s8[1][k] + s8[2][k] + s8[3][k]
                + s8[4][k] + s8[5][k] + s8[6][k] + s8[7][k];
        ws[WS_S + (size_t)blk * RK + k] = v;
    }
    grid.sync();

    // ---- Stage D: tiled GEMM, grid remapped ----
    {
        const int bvt = blk % 12;
        const int ft  = (blk / 12) & 3;
        const int ks  = blk / 48;
        const int bv0 = bvt * 16, f0 = ft * 32, k0 = ks * 384;

        // s_tile: wave per bv row, 6 x 256B coalesced reads
        {
            const float* src = ws + WS_S + (size_t)(bv0 + wave) * RK + k0;
#pragma unroll
            for (int j = 0; j < 6; ++j) s_tile[wave][j * 64 + lane] = src[j * 64 + lane];
        }
        for (int i = tid; i < 384 * 32; i += 1024) {
            const int k = i >> 5, f = i & 31;
            w_tile[k][f] = W[(size_t)(k0 + k) * FF + f0 + f];
        }
        __syncthreads();

        if (tid < 512) {
            const int g = tid >> 5, f_l = tid & 31;
            float acc = 0.f;
#pragma unroll 4
            for (int k = 0; k < 384; k += 4) {
                const float4 sv = *(const float4*)&s_tile[g][k];
                acc += sv.x * w_tile[k][f_l]     + sv.y * w_tile[k + 1][f_l]
                     + sv.z * w_tile[k + 2][f_l] + sv.w * w_tile[k + 3][f_l];
            }
            atomicAdd(&out[(size_t)(bv0 + g) * FF + f0 + f_l], acc);
        }
    }
}

extern "C" void kernel_launch(void* const* d_in, const int* in_sizes, int n_in,
                              void* d_out, int out_size, void* d_ws, size_t ws_size,
                              hipStream_t stream) {
    const float* fe  = (const float*)d_in[0];  // feature_embed   (B,V,N,E)
    const float* ne  = (const float*)d_in[1];  // neighbour_embed (B,V,N,E)
    const int*   wi  = (const int*)d_in[2];    // w_index (B,V,N)
    const float* ind = (const float*)d_in[3];  // indicator (B,V,N)
    const float* W   = (const float*)d_in[4];  // (12,E,F)
    const float* a   = (const float*)d_in[5];  // (2F,1)
    float* out = (float*)d_out;                // (B,V,F)
    float* ws  = (float*)d_ws;

    void* args[] = {(void*)&fe, (void*)&ne, (void*)&wi, (void*)&ind,
                    (void*)&W, (void*)&a, (void*)&out, (void*)&ws};
    hipLaunchCooperativeKernel((const void*)gat_coop, dim3(BV), dim3(1024),
                               args, 0, stream);
}

// Round 5
// 46.600 us; speedup vs baseline: 1.5825x; 1.5825x over previous
//
#include <hip/hip_runtime.h>

#define NREL1 12   // NREL + 1 relation matrices
#define NN    128  // neighbours
#define EE    128  // in-features
#define FF    128  // out-features
#define BV    192  // B * V
#define RK    (NREL1 * EE)   // 1536

// Single fused kernel: block per (b,v), 1024 threads (16 waves).
// - prefetch this bv's fe/ne rows into regs (8 edges/wave, lanes<32 ne, >=32 fe)
// - Phase 0: wa1/wa2 = W@a1, W@a2; half-wave per row, 1KB coalesced wave-instr
// - Phase A: logits from regs + wa in LDS, full-wave butterfly
// - Phase B: softmax + indicator (wave 0)
// - Phase C: scatter from regs into s16[wave] (16 private copies, race-free)
// - Phase D: out = S @ W, thread owns f-quad x k-group, coalesced 1KB W reads
__global__ __launch_bounds__(1024) void gat_fused(const float* __restrict__ fe,
                                                  const float* __restrict__ ne,
                                                  const int* __restrict__ widx,
                                                  const float* __restrict__ ind,
                                                  const float* __restrict__ W,
                                                  const float* __restrict__ a,
                                                  float* __restrict__ out) {
    __shared__ float wa[2 * RK];     // 12 KB; wa1 | wa2. Reused: wa[0..RK) = S after reduce
    __shared__ float s16[16][RK];    // 96 KB, one scatter copy per wave
    __shared__ float red[32][FF];    // 16 KB
    __shared__ float red2[4][FF];    // 2 KB
    __shared__ float e_lds[NN];
    __shared__ float attn[NN];
    __shared__ int   idx[NN];

    const int bv   = blockIdx.x;
    const int tid  = threadIdx.x;
    const int wave = tid >> 6;
    const int lane = tid & 63;
    const int l32  = lane & 31;
    const int half = lane >> 5;   // 0: ne/wa1 side, 1: fe/wa2 side

    const float* ne_bv = ne + (size_t)bv * NN * EE;
    const float* fe_bv = fe + (size_t)bv * NN * EE;

    if (tid < NN) idx[tid] = widx[bv * NN + tid];
    for (int i = tid; i < 16 * RK; i += 1024) (&s16[0][0])[i] = 0.f;

    // ---- prefetch: 8 edges per wave; lane holds one f-quad of ne (or fe) ----
    float4 xr[8];
    {
        const float* base = (half ? fe_bv : ne_bv) + l32 * 4;
#pragma unroll
        for (int i = 0; i < 8; ++i)
            xr[i] = *(const float4*)(base + (wave * 8 + i) * EE);
    }
    const float4 a1q = *(const float4*)(a + l32 * 4);
    const float4 a2q = *(const float4*)(a + FF + l32 * 4);

    // ---- Phase 0: wa rows; half-wave per row, 1KB contiguous per wave-instr ----
#pragma unroll 2
    for (int it = 0; it < 48; ++it) {
        const int row = it * 32 + wave * 2 + half;
        const float4 wv = *(const float4*)(W + (size_t)row * FF + l32 * 4);
        float d1 = wv.x * a1q.x + wv.y * a1q.y + wv.z * a1q.z + wv.w * a1q.w;
        float d2 = wv.x * a2q.x + wv.y * a2q.y + wv.z * a2q.z + wv.w * a2q.w;
#pragma unroll
        for (int off = 16; off; off >>= 1) {
            d1 += __shfl_xor(d1, off);
            d2 += __shfl_xor(d2, off);
        }
        if (l32 == 0) { wa[row] = d1; wa[RK + row] = d2; }
    }
    __syncthreads();

    // ---- Phase A: logits; lanes<32 contribute ne.wa1, lanes>=32 fe.wa2 ----
#pragma unroll
    for (int i = 0; i < 8; ++i) {
        const int n = wave * 8 + i;
        const int r = idx[n];
        const float4 wq = *(const float4*)(&wa[half * RK + r * EE + l32 * 4]);
        float d = xr[i].x * wq.x + xr[i].y * wq.y + xr[i].z * wq.z + xr[i].w * wq.w;
#pragma unroll
        for (int off = 32; off; off >>= 1) d += __shfl_xor(d, off);
        if (lane == 0) e_lds[n] = d > 0.f ? d : 0.2f * d;
    }
    __syncthreads();

    // ---- Phase B: softmax over neighbours + indicator mask (wave 0) ----
    if (tid < 64) {
        float v0 = e_lds[tid], v1 = e_lds[tid + 64];
        float m = fmaxf(v0, v1);
#pragma unroll
        for (int off = 32; off; off >>= 1) m = fmaxf(m, __shfl_xor(m, off));
        float ex0 = expf(v0 - m), ex1 = expf(v1 - m);
        float ssum = ex0 + ex1;
#pragma unroll
        for (int off = 32; off; off >>= 1) ssum += __shfl_xor(ssum, off);
        float inv = 1.f / ssum;
        attn[tid]      = ex0 * inv * ind[bv * NN + tid];
        attn[tid + 64] = ex1 * inv * ind[bv * NN + tid + 64];
    }
    __syncthreads();

    // ---- Phase C: scatter from regs into this wave's private copy ----
    if (half == 0) {
        float* sc = s16[wave];
#pragma unroll
        for (int i = 0; i < 8; ++i) {
            const int n = wave * 8 + i;
            const float an = attn[n];
            const int r = idx[n];
            float* p = sc + r * EE + l32 * 4;
            float4 cur = *(const float4*)p;
            cur.x += an * xr[i].x; cur.y += an * xr[i].y;
            cur.z += an * xr[i].z; cur.w += an * xr[i].w;
            *(float4*)p = cur;
        }
    }
    __syncthreads();

    // ---- reduce 16 copies -> S in wa[0..RK) (wa1/wa2 dead after Phase A) ----
    for (int k = tid; k < RK; k += 1024) {
        float v = 0.f;
#pragma unroll
        for (int c = 0; c < 16; ++c) v += s16[c][k];
        wa[k] = v;
    }
    __syncthreads();

    // ---- Phase D: out[f] = sum_k S[k] * W[k][f]; 1KB coalesced W reads ----
    {
        const int f4 = (tid & 31) * 4;
        const int kg = tid >> 5;          // 0..31, owns k in [kg*48, kg*48+48)
        float4 acc = {0.f, 0.f, 0.f, 0.f};
        const float* Wp = W + f4;
#pragma unroll 4
        for (int j = 0; j < 48; ++j) {
            const int k = kg * 48 + j;
            const float sv = wa[k];
            const float4 wv = *(const float4*)(Wp + (size_t)k * FF);
            acc.x += sv * wv.x; acc.y += sv * wv.y;
            acc.z += sv * wv.z; acc.w += sv * wv.w;
        }
        *(float4*)&red[kg][f4] = acc;
    }
    __syncthreads();
    if (tid < 512) {
        const int q = tid >> 7, f = tid & 127;
        float v = 0.f;
#pragma unroll
        for (int j = 0; j < 8; ++j) v += red[q * 8 + j][f];
        red2[q][f] = v;
    }
    __syncthreads();
    if (tid < FF)
        out[bv * FF + tid] = red2[0][tid] + red2[1][tid] + red2[2][tid] + red2[3][tid];
}

extern "C" void kernel_launch(void* const* d_in, const int* in_sizes, int n_in,
                              void* d_out, int out_size, void* d_ws, size_t ws_size,
                              hipStream_t stream) {
    const float* fe  = (const float*)d_in[0];  // feature_embed   (B,V,N,E)
    const float* ne  = (const float*)d_in[1];  // neighbour_embed (B,V,N,E)
    const int*   wi  = (const int*)d_in[2];    // w_index (B,V,N)
    const float* ind = (const float*)d_in[3];  // indicator (B,V,N)
    const float* W   = (const float*)d_in[4];  // (12,E,F)
    const float* a   = (const float*)d_in[5];  // (2F,1)
    float* out = (float*)d_out;                // (B,V,F)

    gat_fused<<<BV, 1024, 0, stream>>>(fe, ne, wi, ind, W, a, out);
}